// Round 1
// baseline (542.380 us; speedup 1.0000x reference)
//
#include <hip/hip_runtime.h>
#include <hip/hip_bf16.h>

// MLA prefill: B=1, T=2048, C=2048, H=16, DN=128, DR=64, DV=128, QKD=192,
// RQ=1536, RKV=512. Inputs f32, output f32.
// Round 7: latency-bound fixes.
//  - GEMM: 2-phase LDS double-buffer (stage k+1 before compute k, one barrier
//    per K-step) -- hides global_load_lds latency at our 0.3-2 block/CU grids.
//  - attn: T14 async-STAGE split (prefetch next K/V tile into regs during
//    compute; only ds_writes between barriers) + T5 setprio around MFMA.

#define T_DIM 2048
#define H_DIM 16
#define SCALE_F 0.07216878364870322f   // 192^-0.5
#define EPS_F 1e-6f
#define NEG_INF (-3.402823466e38f)

typedef __attribute__((ext_vector_type(8))) short short8;
typedef __attribute__((ext_vector_type(4))) float f32x4;
typedef __attribute__((address_space(3))) char lds_char;
typedef const __attribute__((address_space(1))) char glb_char;

__device__ inline void st_out(float* p, float v) { *p = v; }
__device__ inline void st_out(__hip_bfloat16* p, float v) { *p = __float2bfloat16(v); }

// ---------------- f32 -> bf16 cast (optionally zero-padded tail) ------------
__global__ void cast_bf16_kernel(const float* __restrict__ src,
                                 __hip_bfloat16* __restrict__ dst,
                                 int n4_src, int n4_dst) {
    int i = blockIdx.x * 256 + threadIdx.x;
    if (i >= n4_dst) return;
    float4 v = make_float4(0.f, 0.f, 0.f, 0.f);
    if (i < n4_src) v = ((const float4*)src)[i];
    dst[4 * i + 0] = __float2bfloat16(v.x);
    dst[4 * i + 1] = __float2bfloat16(v.y);
    dst[4 * i + 2] = __float2bfloat16(v.z);
    dst[4 * i + 3] = __float2bfloat16(v.w);
}

__global__ void pad_bias_kernel(const float* __restrict__ src, float* __restrict__ dst,
                                int n_src, int n_dst) {
    int i = blockIdx.x * 256 + threadIdx.x;
    if (i < n_dst) dst[i] = (i < n_src) ? src[i] : 0.f;
}

// ---------------- MFMA GEMM: C[M,N] = A[M,K] @ W[N,K]^T + bias[N] -----------
// A,W bf16; bias f32; OT out. M%128==0 (grid.y), N%128==0 (grid.x), K%32==0.
// 256 threads = 4 waves; wave owns a 64x64 quadrant (4x4 MFMA 16x16x32 tiles).
// 2-phase double-buffer: stage tile k+1 into buf^1 BEFORE ds_read+MFMA of
// buf, then one __syncthreads (drains vmcnt+lgkm) per step. Load latency
// hides under compute -- critical at grids with <2 blocks/CU.
template <typename OT>
__global__ __launch_bounds__(256) void gemm_mfma_kernel(
    const __hip_bfloat16* __restrict__ A, int lda,
    const __hip_bfloat16* __restrict__ W, int ldw,
    const float* __restrict__ bias,
    OT* __restrict__ C, int ldc, int K) {
    __shared__ __hip_bfloat16 As[2][128 * 32];
    __shared__ __hip_bfloat16 Bs[2][128 * 32];
    const int tid = threadIdx.x;
    const int w = tid >> 6, lane = tid & 63, qd = lane >> 4, lx = lane & 15;
    const int rowB = blockIdx.y * 128, colB = blockIdx.x * 128;
    const int wr = (w >> 1) * 64, wc = (w & 1) * 64;

    f32x4 acc[4][4];
#pragma unroll
    for (int i = 0; i < 4; ++i)
#pragma unroll
        for (int j = 0; j < 4; ++j) acc[i][j] = (f32x4)(0.f);

    auto stage = [&](int buf, int k0) {
#pragma unroll
        for (int it = 0; it < 2; ++it) {
            const int g = w * 128 + it * 64 + lane;   // 16B granule index
            const int row = g >> 2, q = g & 3;
            const __hip_bfloat16* ga = A + (size_t)(rowB + row) * lda + k0 + q * 8;
            __builtin_amdgcn_global_load_lds((glb_char*)ga,
                (lds_char*)((char*)&As[buf][0] + (size_t)g * 16), 16, 0, 0);
            const __hip_bfloat16* gb = W + (size_t)(colB + row) * ldw + k0 + q * 8;
            __builtin_amdgcn_global_load_lds((glb_char*)gb,
                (lds_char*)((char*)&Bs[buf][0] + (size_t)g * 16), 16, 0, 0);
        }
    };

    stage(0, 0);
    __syncthreads();          // buf0 ready
    int cur = 0;
    for (int k0 = 0; k0 < K; k0 += 32) {
        if (k0 + 32 < K) stage(cur ^ 1, k0 + 32);   // in flight across compute

        short8 a[4], b[4];
#pragma unroll
        for (int rt = 0; rt < 4; ++rt)
            a[rt] = *(const short8*)&As[cur][(wr + rt * 16 + lx) * 32 + qd * 8];
#pragma unroll
        for (int ct = 0; ct < 4; ++ct)
            b[ct] = *(const short8*)&Bs[cur][(wc + ct * 16 + lx) * 32 + qd * 8];
#pragma unroll
        for (int rt = 0; rt < 4; ++rt)
#pragma unroll
            for (int ct = 0; ct < 4; ++ct)
                acc[rt][ct] = __builtin_amdgcn_mfma_f32_16x16x32_bf16(a[rt], b[ct], acc[rt][ct], 0, 0, 0);
        // one barrier/step: drains stage's vmcnt (next buf ready) AND ensures
        // all waves finished reading cur before it is re-staged next step.
        __syncthreads();
        cur ^= 1;
    }

    // epilogue: C/D layout col=lane&15, row=4*qd+reg
#pragma unroll
    for (int rt = 0; rt < 4; ++rt)
#pragma unroll
        for (int j = 0; j < 4; ++j) {
            const int row = rowB + wr + rt * 16 + 4 * qd + j;
#pragma unroll
            for (int ct = 0; ct < 4; ++ct) {
                const int col = colB + wc + ct * 16 + lx;
                st_out(&C[(size_t)row * ldc + col], acc[rt][ct][j] + bias[col]);
            }
        }
}

// ---------------- RMSNorm: f32 in -> bf16 out -------------------------------
__global__ void rmsnorm_kernel(const float* __restrict__ in, __hip_bfloat16* __restrict__ outp,
                               const float* __restrict__ w,
                               int D, int in_stride, int out_stride) {
    const int row = blockIdx.x;
    const float* p = in + (size_t)row * in_stride;
    __hip_bfloat16* o = outp + (size_t)row * out_stride;
    const int tid = threadIdx.x;  // 256
    float ss = 0.f;
    for (int i = tid; i < D; i += 256) { float v = p[i]; ss += v * v; }
    __shared__ float red[256];
    red[tid] = ss;
    __syncthreads();
    for (int off = 128; off > 0; off >>= 1) {
        if (tid < off) red[tid] += red[tid + off];
        __syncthreads();
    }
    const float scale = rsqrtf(red[0] / (float)D + EPS_F);
    for (int i = tid; i < D; i += 256)
        o[i] = __float2bfloat16(p[i] * scale * w[i]);
}

// ---------------- RoPE on q (in-place on bf16 qb: (T, H*192)) ---------------
__global__ void rope_q_bf_kernel(__hip_bfloat16* __restrict__ qb,
                                 const float* __restrict__ freqs) {
    const int idx = blockIdx.x * 256 + threadIdx.x;
    const int t = idx >> 9;
    const int h = (idx >> 5) & 15;
    const int i = idx & 31;
    const float f = freqs[t * 32 + i];
    const float c = cosf(f), s = sinf(f);
    __hip_bfloat16* p = qb + (size_t)t * 3072 + h * 192 + 128 + 2 * i;
    const float xr = __bfloat162float(p[0]), xi = __bfloat162float(p[1]);
    p[0] = __float2bfloat16(xr * c - xi * s);
    p[1] = __float2bfloat16(xr * s + xi * c);
}

// ---------------- RoPE on k_pe: kvpe f32 (T,640) cols[512:576) -> kpe bf16 --
__global__ void rope_k_bf_kernel(const float* __restrict__ kvpe,
                                 const float* __restrict__ freqs,
                                 __hip_bfloat16* __restrict__ kpe) {
    const int idx = blockIdx.x * 256 + threadIdx.x;  // 65536
    const int t = idx >> 5;
    const int i = idx & 31;
    const float f = freqs[t * 32 + i];
    const float c = cosf(f), s = sinf(f);
    const float* src = kvpe + (size_t)t * 640 + 512 + 2 * i;
    const float xr = src[0], xi = src[1];
    kpe[(size_t)t * 64 + 2 * i]     = __float2bfloat16(xr * c - xi * s);
    kpe[(size_t)t * 64 + 2 * i + 1] = __float2bfloat16(xr * s + xi * c);
}

// ---------------- pack V transposed: kvb_bf (T,H*256) -> vT (H,128,T) -------
__global__ void pack_vT_kernel(const __hip_bfloat16* __restrict__ kvb,
                               __hip_bfloat16* __restrict__ vT) {
    const int t0 = blockIdx.x * 64;
    const int h = blockIdx.y;
    const int tid = threadIdx.x;
    __shared__ __hip_bfloat16 Ls[64][136];
#pragma unroll
    for (int it = 0; it < 4; ++it) {
        int c = tid + 256 * it;
        int i = c >> 4, part = c & 15;
        *(uint4*)&Ls[i][part * 8] =
            *(const uint4*)(kvb + (size_t)(t0 + i) * 4096 + h * 256 + 128 + part * 8);
    }
    __syncthreads();
#pragma unroll
    for (int it = 0; it < 32; ++it) {
        int c = tid + 256 * it;
        int d = c >> 6, i = c & 63;
        vT[((size_t)(h * 128 + d)) * 2048 + t0 + i] = Ls[i][d];
    }
}

// ---------------- MFMA flash attention (y out in bf16) ----------------------
// Round 7: T14 async-STAGE split. Next tile's K/V/kpe are fetched into 10
// uint4 registers right after the staging barrier, so HBM/L2 latency hides
// under QK+softmax+PV of the current tile. Loop head then only does
// reg->LDS ds_writes between the two barriers. T5 setprio around MFMA.
__global__ __launch_bounds__(256) void attn_mfma_kernel(
    const __hip_bfloat16* __restrict__ q,
    const __hip_bfloat16* __restrict__ kv,
    const __hip_bfloat16* __restrict__ kpe,
    const __hip_bfloat16* __restrict__ vT,
    __hip_bfloat16* __restrict__ y) {
    const int qt = gridDim.x - 1 - blockIdx.x;   // longest blocks first
    const int h = blockIdx.y;
    const int q0 = qt * 64;
    const int tid = threadIdx.x;
    const int w = tid >> 6, lane = tid & 63, qd = lane >> 4, lx = lane & 15;

    __shared__ __hip_bfloat16 Ks[64][200];
    __shared__ __hip_bfloat16 Vs[128][72];
    __shared__ __hip_bfloat16 Ps[4][16][72];

    short8 qf[6];
    {
        const __hip_bfloat16* qrow =
            q + (size_t)(q0 + 16 * w + lx) * 3072 + h * 192 + qd * 8;
#pragma unroll
        for (int kc = 0; kc < 6; ++kc)
            qf[kc] = *(const short8*)(qrow + kc * 32);
    }

    f32x4 O[8];
#pragma unroll
    for (int i = 0; i < 8; ++i) O[i] = (f32x4)(0.f);
    float mrow[4], lrow[4];
#pragma unroll
    for (int j = 0; j < 4; ++j) { mrow[j] = NEG_INF; lrow[j] = 0.f; }

    // prefetch registers: K main 4x16B, kpe 2x16B, V 4x16B per thread
    uint4 kreg[4], kpereg[2], vreg[4];
    auto prefetch = [&](int s0) {
#pragma unroll
        for (int it = 0; it < 4; ++it) {
            int c = tid + 256 * it;
            kreg[it] = *(const uint4*)(kv + (size_t)(s0 + (c >> 4)) * 4096 + h * 256 + (c & 15) * 8);
        }
#pragma unroll
        for (int it = 0; it < 2; ++it) {
            int c = tid + 256 * it;
            kpereg[it] = *(const uint4*)(kpe + (size_t)(s0 + (c >> 3)) * 64 + (c & 7) * 8);
        }
#pragma unroll
        for (int it = 0; it < 4; ++it) {
            int c = tid + 256 * it;
            vreg[it] = *(const uint4*)(vT + ((size_t)(h * 128 + (c >> 3))) * 2048 + s0 + (c & 7) * 8);
        }
    };
    prefetch(0);

    for (int s0 = 0; s0 <= q0 + 63; s0 += 64) {
        __syncthreads();   // all waves done reading LDS of previous tile
        // reg -> LDS (regs hold tile s0, prefetched last iteration/prologue)
#pragma unroll
        for (int it = 0; it < 4; ++it) {
            int c = tid + 256 * it;
            *(uint4*)&Ks[c >> 4][(c & 15) * 8] = kreg[it];
        }
#pragma unroll
        for (int it = 0; it < 2; ++it) {
            int c = tid + 256 * it;
            *(uint4*)&Ks[c >> 3][128 + (c & 7) * 8] = kpereg[it];
        }
#pragma unroll
        for (int it = 0; it < 4; ++it) {
            int c = tid + 256 * it;
            *(uint4*)&Vs[c >> 3][(c & 7) * 8] = vreg[it];
        }
        __syncthreads();   // tile visible to all waves

        // issue next tile's global loads NOW; drained by the waitcnt the
        // compiler inserts before next iteration's reg->LDS writes -- i.e.
        // latency hides under QK+softmax+PV below.
        if (s0 + 64 <= q0) prefetch(s0 + 64);

        f32x4 S[4];
#pragma unroll
        for (int nt = 0; nt < 4; ++nt) S[nt] = (f32x4)(0.f);
        __builtin_amdgcn_s_setprio(1);
#pragma unroll
        for (int kc = 0; kc < 6; ++kc) {
            short8 a = qf[kc];
#pragma unroll
            for (int nt = 0; nt < 4; ++nt) {
                short8 b = *(const short8*)&Ks[nt * 16 + lx][kc * 32 + qd * 8];
                S[nt] = __builtin_amdgcn_mfma_f32_16x16x32_bf16(a, b, S[nt], 0, 0, 0);
            }
        }
        __builtin_amdgcn_s_setprio(0);

        float sv[4][4];
#pragma unroll
        for (int nt = 0; nt < 4; ++nt) {
            int col = s0 + nt * 16 + lx;
#pragma unroll
            for (int j = 0; j < 4; ++j) {
                int row = q0 + 16 * w + 4 * qd + j;
                float v = S[nt][j] * SCALE_F;
                sv[nt][j] = (col > row) ? NEG_INF : v;
            }
        }

        float mn[4], al[4], rs[4];
#pragma unroll
        for (int j = 0; j < 4; ++j) {
            float rm = fmaxf(fmaxf(sv[0][j], sv[1][j]), fmaxf(sv[2][j], sv[3][j]));
#pragma unroll
            for (int msk = 1; msk < 16; msk <<= 1)
                rm = fmaxf(rm, __shfl_xor(rm, msk));
            mn[j] = fmaxf(mrow[j], rm);
            al[j] = __expf(mrow[j] - mn[j]);
            rs[j] = 0.f;
        }
#pragma unroll
        for (int nt = 0; nt < 4; ++nt)
#pragma unroll
            for (int j = 0; j < 4; ++j) {
                float p = __expf(sv[nt][j] - mn[j]);
                rs[j] += p;
                Ps[w][4 * qd + j][nt * 16 + lx] = __float2bfloat16(p);
            }
#pragma unroll
        for (int j = 0; j < 4; ++j) {
#pragma unroll
            for (int msk = 1; msk < 16; msk <<= 1)
                rs[j] += __shfl_xor(rs[j], msk);
            lrow[j] = lrow[j] * al[j] + rs[j];
            mrow[j] = mn[j];
        }
#pragma unroll
        for (int nt = 0; nt < 8; ++nt)
#pragma unroll
            for (int j = 0; j < 4; ++j) O[nt][j] *= al[j];

        asm volatile("s_waitcnt lgkmcnt(0)" ::: "memory");

        __builtin_amdgcn_s_setprio(1);
#pragma unroll
        for (int kc2 = 0; kc2 < 2; ++kc2) {
            short8 pa = *(const short8*)&Ps[w][lx][kc2 * 32 + qd * 8];
#pragma unroll
            for (int nt = 0; nt < 8; ++nt) {
                short8 vb = *(const short8*)&Vs[nt * 16 + lx][kc2 * 32 + qd * 8];
                O[nt] = __builtin_amdgcn_mfma_f32_16x16x32_bf16(pa, vb, O[nt], 0, 0, 0);
            }
        }
        __builtin_amdgcn_s_setprio(0);
    }

#pragma unroll
    for (int j = 0; j < 4; ++j) {
        const float inv = 1.f / lrow[j];
        const int t = q0 + 16 * w + 4 * qd + j;
        __hip_bfloat16* yr = y + (size_t)t * 2048 + h * 128 + lx;
#pragma unroll
        for (int nt = 0; nt < 8; ++nt) yr[nt * 16] = __float2bfloat16(O[nt][j] * inv);
    }
}

extern "C" void kernel_launch(void* const* d_in, const int* in_sizes, int n_in,
                              void* d_out, int out_size, void* d_ws, size_t ws_size,
                              hipStream_t stream) {
    const float* x         = (const float*)d_in[0];
    const float* freqs     = (const float*)d_in[1];
    const float* wq_a      = (const float*)d_in[2];
    const float* bq_a      = (const float*)d_in[3];
    const float* q_norm_w  = (const float*)d_in[4];
    const float* wq_b      = (const float*)d_in[5];
    const float* bq_b      = (const float*)d_in[6];
    const float* wkv_a     = (const float*)d_in[7];
    const float* bkv_a     = (const float*)d_in[8];
    const float* kv_norm_w = (const float*)d_in[9];
    const float* wkv_b     = (const float*)d_in[10];
    const float* bkv_b     = (const float*)d_in[11];
    const float* wo        = (const float*)d_in[12];
    const float* bo        = (const float*)d_in[13];
    float* out = (float*)d_out;

    // Workspace layout, ~76.3 MB total.
    char* p = (char*)d_ws;
    float* q_lat = (float*)p;                        p += (size_t)2048 * 1536 * 4;  // later hosts yb_bf
    float* kvpe  = (float*)p;                        p += (size_t)2048 * 640 * 4;
    __hip_bfloat16* x_bf      = (__hip_bfloat16*)p;  p += (size_t)2048 * 2048 * 2;  // later hosts vT
    __hip_bfloat16* q_lat_bf  = (__hip_bfloat16*)p;  p += (size_t)2048 * 1536 * 2;
    __hip_bfloat16* qb_bf     = (__hip_bfloat16*)p;  p += (size_t)2048 * 3072 * 2;
    __hip_bfloat16* kv_lat_bf = (__hip_bfloat16*)p;  p += (size_t)2048 * 512 * 2;
    __hip_bfloat16* kvb_bf    = (__hip_bfloat16*)p;  p += (size_t)2048 * 4096 * 2;
    __hip_bfloat16* kpe_bf    = (__hip_bfloat16*)p;  p += (size_t)2048 * 64 * 2;
    __hip_bfloat16* WA        = (__hip_bfloat16*)p;  p += (size_t)3072 * 1536 * 2;  // weight arena (max 9.44 MB)
    __hip_bfloat16* WB        = (__hip_bfloat16*)p;  p += (size_t)640 * 2048 * 2;   // padded wkv_a
    float* bkv_pad = (float*)p;                      p += (size_t)640 * 4;
    __hip_bfloat16* vT    = x_bf;                    // alias: x_bf dead after GEMM 2
    __hip_bfloat16* yb_bf = (__hip_bfloat16*)q_lat;  // alias: q_lat dead after rmsnorm

    // ---- casts & pads ----
    cast_bf16_kernel<<<4096, 256, 0, stream>>>(x, x_bf, 1048576, 1048576);
    cast_bf16_kernel<<<3072, 256, 0, stream>>>(wq_a, WA, 786432, 786432);
    // GEMM 1: q_lat = x @ wq_a^T + bq_a  (f32 out)
    gemm_mfma_kernel<float><<<dim3(12, 16), 256, 0, stream>>>(x_bf, 2048, WA, 2048, bq_a, q_lat, 1536, 2048);
    cast_bf16_kernel<<<1280, 256, 0, stream>>>(wkv_a, WB, 294912, 327680);
    pad_bias_kernel<<<3, 256, 0, stream>>>(bkv_a, bkv_pad, 576, 640);
    // GEMM 2: kvpe = x @ wkv_a^T + bkv_a  (f32 out, N padded to 640)
    gemm_mfma_kernel<float><<<dim3(5, 16), 256, 0, stream>>>(x_bf, 2048, WB, 2048, bkv_pad, kvpe, 640, 2048);
    // rmsnorm q -> bf16
    rmsnorm_kernel<<<2048, 256, 0, stream>>>(q_lat, q_lat_bf, q_norm_w, 1536, 1536, 1536);
    cast_bf16_kernel<<<4608, 256, 0, stream>>>(wq_b, WA, 1179648, 1179648);
    // GEMM 3: qb_bf = q_lat_bf @ wq_b^T + bq_b
    gemm_mfma_kernel<__hip_bfloat16><<<dim3(24, 16), 256, 0, stream>>>(q_lat_bf, 1536, WA, 1536, bq_b, qb_bf, 3072, 1536);
    rope_q_bf_kernel<<<4096, 256, 0, stream>>>(qb_bf, freqs);
    rope_k_bf_kernel<<<256, 256, 0, stream>>>(kvpe, freqs, kpe_bf);
    rmsnorm_kernel<<<2048, 256, 0, stream>>>(kvpe, kv_lat_bf, kv_norm_w, 512, 640, 512);
    cast_bf16_kernel<<<2048, 256, 0, stream>>>(wkv_b, WA, 524288, 524288);
    // GEMM 4: kvb_bf = kv_lat_bf @ wkv_b^T + bkv_b
    gemm_mfma_kernel<__hip_bfloat16><<<dim3(32, 16), 256, 0, stream>>>(kv_lat_bf, 512, WA, 512, bkv_b, kvb_bf, 4096, 512);
    pack_vT_kernel<<<dim3(32, 16), 256, 0, stream>>>(kvb_bf, vT);
    attn_mfma_kernel<<<dim3(32, 16), 256, 0, stream>>>(qb_bf, kvb_bf, kpe_bf, vT, yb_bf);
    cast_bf16_kernel<<<4096, 256, 0, stream>>>(wo, WA, 1048576, 1048576);
    // GEMM 5: out = yb_bf @ wo^T + bo  (f32 out)
    gemm_mfma_kernel<float><<<dim3(16, 16), 256, 0, stream>>>(yb_bf, 2048, WA, 2048, bo, out, 2048, 2048);
}

// Round 2
// 450.691 us; speedup vs baseline: 1.2034x; 1.2034x over previous
//
#include <hip/hip_runtime.h>
#include <hip/hip_bf16.h>

// MLA prefill: B=1, T=2048, C=2048, H=16, DN=128, DR=64, DV=128, QKD=192,
// RQ=1536, RKV=512. Inputs f32, output f32.
// Round 8: attn T14 redone with NAMED uint4 prefetch registers (round 7's
// array-in-lambda version went to scratch: WRITE_SIZE 8MB->197MB). GEMM keeps
// the 2-phase double-buffer (it improved the non-attn portion ~17us).

#define T_DIM 2048
#define H_DIM 16
#define SCALE_F 0.07216878364870322f   // 192^-0.5
#define EPS_F 1e-6f
#define NEG_INF (-3.402823466e38f)

typedef __attribute__((ext_vector_type(8))) short short8;
typedef __attribute__((ext_vector_type(4))) float f32x4;
typedef __attribute__((address_space(3))) char lds_char;
typedef const __attribute__((address_space(1))) char glb_char;

__device__ inline void st_out(float* p, float v) { *p = v; }
__device__ inline void st_out(__hip_bfloat16* p, float v) { *p = __float2bfloat16(v); }

// ---------------- f32 -> bf16 cast (optionally zero-padded tail) ------------
__global__ void cast_bf16_kernel(const float* __restrict__ src,
                                 __hip_bfloat16* __restrict__ dst,
                                 int n4_src, int n4_dst) {
    int i = blockIdx.x * 256 + threadIdx.x;
    if (i >= n4_dst) return;
    float4 v = make_float4(0.f, 0.f, 0.f, 0.f);
    if (i < n4_src) v = ((const float4*)src)[i];
    dst[4 * i + 0] = __float2bfloat16(v.x);
    dst[4 * i + 1] = __float2bfloat16(v.y);
    dst[4 * i + 2] = __float2bfloat16(v.z);
    dst[4 * i + 3] = __float2bfloat16(v.w);
}

__global__ void pad_bias_kernel(const float* __restrict__ src, float* __restrict__ dst,
                                int n_src, int n_dst) {
    int i = blockIdx.x * 256 + threadIdx.x;
    if (i < n_dst) dst[i] = (i < n_src) ? src[i] : 0.f;
}

// ---------------- MFMA GEMM: C[M,N] = A[M,K] @ W[N,K]^T + bias[N] -----------
// A,W bf16; bias f32; OT out. M%128==0 (grid.y), N%128==0 (grid.x), K%32==0.
// 256 threads = 4 waves; wave owns a 64x64 quadrant (4x4 MFMA 16x16x32 tiles).
// 2-phase double-buffer: stage tile k+1 into buf^1 BEFORE ds_read+MFMA of
// buf, then one __syncthreads per step.
template <typename OT>
__global__ __launch_bounds__(256) void gemm_mfma_kernel(
    const __hip_bfloat16* __restrict__ A, int lda,
    const __hip_bfloat16* __restrict__ W, int ldw,
    const float* __restrict__ bias,
    OT* __restrict__ C, int ldc, int K) {
    __shared__ __hip_bfloat16 As[2][128 * 32];
    __shared__ __hip_bfloat16 Bs[2][128 * 32];
    const int tid = threadIdx.x;
    const int w = tid >> 6, lane = tid & 63, qd = lane >> 4, lx = lane & 15;
    const int rowB = blockIdx.y * 128, colB = blockIdx.x * 128;
    const int wr = (w >> 1) * 64, wc = (w & 1) * 64;

    f32x4 acc[4][4];
#pragma unroll
    for (int i = 0; i < 4; ++i)
#pragma unroll
        for (int j = 0; j < 4; ++j) acc[i][j] = (f32x4)(0.f);

    auto stage = [&](int buf, int k0) {
#pragma unroll
        for (int it = 0; it < 2; ++it) {
            const int g = w * 128 + it * 64 + lane;   // 16B granule index
            const int row = g >> 2, q = g & 3;
            const __hip_bfloat16* ga = A + (size_t)(rowB + row) * lda + k0 + q * 8;
            __builtin_amdgcn_global_load_lds((glb_char*)ga,
                (lds_char*)((char*)&As[buf][0] + (size_t)g * 16), 16, 0, 0);
            const __hip_bfloat16* gb = W + (size_t)(colB + row) * ldw + k0 + q * 8;
            __builtin_amdgcn_global_load_lds((glb_char*)gb,
                (lds_char*)((char*)&Bs[buf][0] + (size_t)g * 16), 16, 0, 0);
        }
    };

    stage(0, 0);
    __syncthreads();          // buf0 ready
    int cur = 0;
    for (int k0 = 0; k0 < K; k0 += 32) {
        if (k0 + 32 < K) stage(cur ^ 1, k0 + 32);   // in flight across compute

        short8 a[4], b[4];
#pragma unroll
        for (int rt = 0; rt < 4; ++rt)
            a[rt] = *(const short8*)&As[cur][(wr + rt * 16 + lx) * 32 + qd * 8];
#pragma unroll
        for (int ct = 0; ct < 4; ++ct)
            b[ct] = *(const short8*)&Bs[cur][(wc + ct * 16 + lx) * 32 + qd * 8];
#pragma unroll
        for (int rt = 0; rt < 4; ++rt)
#pragma unroll
            for (int ct = 0; ct < 4; ++ct)
                acc[rt][ct] = __builtin_amdgcn_mfma_f32_16x16x32_bf16(a[rt], b[ct], acc[rt][ct], 0, 0, 0);
        __syncthreads();
        cur ^= 1;
    }

    // epilogue: C/D layout col=lane&15, row=4*qd+reg
#pragma unroll
    for (int rt = 0; rt < 4; ++rt)
#pragma unroll
        for (int j = 0; j < 4; ++j) {
            const int row = rowB + wr + rt * 16 + 4 * qd + j;
#pragma unroll
            for (int ct = 0; ct < 4; ++ct) {
                const int col = colB + wc + ct * 16 + lx;
                st_out(&C[(size_t)row * ldc + col], acc[rt][ct][j] + bias[col]);
            }
        }
}

// ---------------- RMSNorm: f32 in -> bf16 out -------------------------------
__global__ void rmsnorm_kernel(const float* __restrict__ in, __hip_bfloat16* __restrict__ outp,
                               const float* __restrict__ w,
                               int D, int in_stride, int out_stride) {
    const int row = blockIdx.x;
    const float* p = in + (size_t)row * in_stride;
    __hip_bfloat16* o = outp + (size_t)row * out_stride;
    const int tid = threadIdx.x;  // 256
    float ss = 0.f;
    for (int i = tid; i < D; i += 256) { float v = p[i]; ss += v * v; }
    __shared__ float red[256];
    red[tid] = ss;
    __syncthreads();
    for (int off = 128; off > 0; off >>= 1) {
        if (tid < off) red[tid] += red[tid + off];
        __syncthreads();
    }
    const float scale = rsqrtf(red[0] / (float)D + EPS_F);
    for (int i = tid; i < D; i += 256)
        o[i] = __float2bfloat16(p[i] * scale * w[i]);
}

// ---------------- RoPE on q (in-place on bf16 qb: (T, H*192)) ---------------
__global__ void rope_q_bf_kernel(__hip_bfloat16* __restrict__ qb,
                                 const float* __restrict__ freqs) {
    const int idx = blockIdx.x * 256 + threadIdx.x;
    const int t = idx >> 9;
    const int h = (idx >> 5) & 15;
    const int i = idx & 31;
    const float f = freqs[t * 32 + i];
    const float c = cosf(f), s = sinf(f);
    __hip_bfloat16* p = qb + (size_t)t * 3072 + h * 192 + 128 + 2 * i;
    const float xr = __bfloat162float(p[0]), xi = __bfloat162float(p[1]);
    p[0] = __float2bfloat16(xr * c - xi * s);
    p[1] = __float2bfloat16(xr * s + xi * c);
}

// ---------------- RoPE on k_pe: kvpe f32 (T,640) cols[512:576) -> kpe bf16 --
__global__ void rope_k_bf_kernel(const float* __restrict__ kvpe,
                                 const float* __restrict__ freqs,
                                 __hip_bfloat16* __restrict__ kpe) {
    const int idx = blockIdx.x * 256 + threadIdx.x;  // 65536
    const int t = idx >> 5;
    const int i = idx & 31;
    const float f = freqs[t * 32 + i];
    const float c = cosf(f), s = sinf(f);
    const float* src = kvpe + (size_t)t * 640 + 512 + 2 * i;
    const float xr = src[0], xi = src[1];
    kpe[(size_t)t * 64 + 2 * i]     = __float2bfloat16(xr * c - xi * s);
    kpe[(size_t)t * 64 + 2 * i + 1] = __float2bfloat16(xr * s + xi * c);
}

// ---------------- pack V transposed: kvb_bf (T,H*256) -> vT (H,128,T) -------
__global__ void pack_vT_kernel(const __hip_bfloat16* __restrict__ kvb,
                               __hip_bfloat16* __restrict__ vT) {
    const int t0 = blockIdx.x * 64;
    const int h = blockIdx.y;
    const int tid = threadIdx.x;
    __shared__ __hip_bfloat16 Ls[64][136];
#pragma unroll
    for (int it = 0; it < 4; ++it) {
        int c = tid + 256 * it;
        int i = c >> 4, part = c & 15;
        *(uint4*)&Ls[i][part * 8] =
            *(const uint4*)(kvb + (size_t)(t0 + i) * 4096 + h * 256 + 128 + part * 8);
    }
    __syncthreads();
#pragma unroll
    for (int it = 0; it < 32; ++it) {
        int c = tid + 256 * it;
        int d = c >> 6, i = c & 63;
        vT[((size_t)(h * 128 + d)) * 2048 + t0 + i] = Ls[i][d];
    }
}

// ---------------- MFMA flash attention (y out in bf16) ----------------------
// T14 async-STAGE with NAMED uint4 prefetch scalars (no arrays, no lambda --
// guaranteed register allocation). Next tile's K/kpe/V global loads are
// issued right after the staging barrier; their latency hides under
// QK+softmax+PV. Loop head only does reg->LDS ds_writes between barriers.
// T5 setprio around both MFMA clusters.
__global__ __launch_bounds__(256) void attn_mfma_kernel(
    const __hip_bfloat16* __restrict__ q,
    const __hip_bfloat16* __restrict__ kv,
    const __hip_bfloat16* __restrict__ kpe,
    const __hip_bfloat16* __restrict__ vT,
    __hip_bfloat16* __restrict__ y) {
    const int qt = gridDim.x - 1 - blockIdx.x;   // longest blocks first
    const int h = blockIdx.y;
    const int q0 = qt * 64;
    const int tid = threadIdx.x;
    const int w = tid >> 6, lane = tid & 63, qd = lane >> 4, lx = lane & 15;

    __shared__ __hip_bfloat16 Ks[64][200];
    __shared__ __hip_bfloat16 Vs[128][72];
    __shared__ __hip_bfloat16 Ps[4][16][72];

    short8 qf[6];
    {
        const __hip_bfloat16* qrow =
            q + (size_t)(q0 + 16 * w + lx) * 3072 + h * 192 + qd * 8;
#pragma unroll
        for (int kc = 0; kc < 6; ++kc)
            qf[kc] = *(const short8*)(qrow + kc * 32);
    }

    f32x4 O[8];
#pragma unroll
    for (int i = 0; i < 8; ++i) O[i] = (f32x4)(0.f);
    float mrow[4], lrow[4];
#pragma unroll
    for (int j = 0; j < 4; ++j) { mrow[j] = NEG_INF; lrow[j] = 0.f; }

    // ---- prefetch state: 10 NAMED uint4 (40 VGPRs), never indexed ----
    uint4 k0r, k1r, k2r, k3r, pe0r, pe1r, v0r, v1r, v2r, v3r;
    const __hip_bfloat16* kvh = kv + h * 256;
    const __hip_bfloat16* vTh = vT + (size_t)h * 128 * 2048;

#define PREFETCH(S0)                                                               \
    do {                                                                           \
        const size_t kk_ = (size_t)(S0) + (tid >> 4);                              \
        const int kp_ = (tid & 15) * 8;                                            \
        k0r = *(const uint4*)(kvh + (kk_ +  0) * 4096 + kp_);                      \
        k1r = *(const uint4*)(kvh + (kk_ + 16) * 4096 + kp_);                      \
        k2r = *(const uint4*)(kvh + (kk_ + 32) * 4096 + kp_);                      \
        k3r = *(const uint4*)(kvh + (kk_ + 48) * 4096 + kp_);                      \
        const size_t pk_ = (size_t)(S0) + (tid >> 3);                              \
        const int pp_ = (tid & 7) * 8;                                             \
        pe0r = *(const uint4*)(kpe + (pk_ +  0) * 64 + pp_);                       \
        pe1r = *(const uint4*)(kpe + (pk_ + 32) * 64 + pp_);                       \
        const __hip_bfloat16* vp_ = vTh + ((size_t)(tid >> 3)) * 2048 + (S0) + pp_;\
        v0r = *(const uint4*)(vp_ + 0 * 65536);                                    \
        v1r = *(const uint4*)(vp_ + 1 * 65536);                                    \
        v2r = *(const uint4*)(vp_ + 2 * 65536);                                    \
        v3r = *(const uint4*)(vp_ + 3 * 65536);                                    \
    } while (0)

    PREFETCH(0);

    for (int s0 = 0; s0 <= q0 + 63; s0 += 64) {
        __syncthreads();   // all waves done reading LDS of previous tile
        // reg -> LDS (regs hold tile s0, prefetched last iteration/prologue)
        {
            const int kr_ = tid >> 4, kp_ = (tid & 15) * 8;
            *(uint4*)&Ks[kr_ +  0][kp_] = k0r;
            *(uint4*)&Ks[kr_ + 16][kp_] = k1r;
            *(uint4*)&Ks[kr_ + 32][kp_] = k2r;
            *(uint4*)&Ks[kr_ + 48][kp_] = k3r;
            const int pr_ = tid >> 3, pp_ = (tid & 7) * 8;
            *(uint4*)&Ks[pr_ +  0][128 + pp_] = pe0r;
            *(uint4*)&Ks[pr_ + 32][128 + pp_] = pe1r;
            *(uint4*)&Vs[pr_ +  0][pp_] = v0r;
            *(uint4*)&Vs[pr_ + 32][pp_] = v1r;
            *(uint4*)&Vs[pr_ + 64][pp_] = v2r;
            *(uint4*)&Vs[pr_ + 96][pp_] = v3r;
        }
        __syncthreads();   // tile visible to all waves

        // issue next tile's global loads NOW; results consumed by next
        // iteration's ds_writes, so latency hides under QK+softmax+PV below.
        if (s0 + 64 <= q0) PREFETCH(s0 + 64);

        f32x4 S[4];
#pragma unroll
        for (int nt = 0; nt < 4; ++nt) S[nt] = (f32x4)(0.f);
        __builtin_amdgcn_s_setprio(1);
#pragma unroll
        for (int kc = 0; kc < 6; ++kc) {
            short8 a = qf[kc];
#pragma unroll
            for (int nt = 0; nt < 4; ++nt) {
                short8 b = *(const short8*)&Ks[nt * 16 + lx][kc * 32 + qd * 8];
                S[nt] = __builtin_amdgcn_mfma_f32_16x16x32_bf16(a, b, S[nt], 0, 0, 0);
            }
        }
        __builtin_amdgcn_s_setprio(0);

        float sv[4][4];
#pragma unroll
        for (int nt = 0; nt < 4; ++nt) {
            int col = s0 + nt * 16 + lx;
#pragma unroll
            for (int j = 0; j < 4; ++j) {
                int row = q0 + 16 * w + 4 * qd + j;
                float v = S[nt][j] * SCALE_F;
                sv[nt][j] = (col > row) ? NEG_INF : v;
            }
        }

        float mn[4], al[4], rs[4];
#pragma unroll
        for (int j = 0; j < 4; ++j) {
            float rm = fmaxf(fmaxf(sv[0][j], sv[1][j]), fmaxf(sv[2][j], sv[3][j]));
#pragma unroll
            for (int msk = 1; msk < 16; msk <<= 1)
                rm = fmaxf(rm, __shfl_xor(rm, msk));
            mn[j] = fmaxf(mrow[j], rm);
            al[j] = __expf(mrow[j] - mn[j]);
            rs[j] = 0.f;
        }
#pragma unroll
        for (int nt = 0; nt < 4; ++nt)
#pragma unroll
            for (int j = 0; j < 4; ++j) {
                float p = __expf(sv[nt][j] - mn[j]);
                rs[j] += p;
                Ps[w][4 * qd + j][nt * 16 + lx] = __float2bfloat16(p);
            }
#pragma unroll
        for (int j = 0; j < 4; ++j) {
#pragma unroll
            for (int msk = 1; msk < 16; msk <<= 1)
                rs[j] += __shfl_xor(rs[j], msk);
            lrow[j] = lrow[j] * al[j] + rs[j];
            mrow[j] = mn[j];
        }
#pragma unroll
        for (int nt = 0; nt < 8; ++nt)
#pragma unroll
            for (int j = 0; j < 4; ++j) O[nt][j] *= al[j];

        asm volatile("s_waitcnt lgkmcnt(0)" ::: "memory");

        __builtin_amdgcn_s_setprio(1);
#pragma unroll
        for (int kc2 = 0; kc2 < 2; ++kc2) {
            short8 pa = *(const short8*)&Ps[w][lx][kc2 * 32 + qd * 8];
#pragma unroll
            for (int nt = 0; nt < 8; ++nt) {
                short8 vb = *(const short8*)&Vs[nt * 16 + lx][kc2 * 32 + qd * 8];
                O[nt] = __builtin_amdgcn_mfma_f32_16x16x32_bf16(pa, vb, O[nt], 0, 0, 0);
            }
        }
        __builtin_amdgcn_s_setprio(0);
    }
#undef PREFETCH

#pragma unroll
    for (int j = 0; j < 4; ++j) {
        const float inv = 1.f / lrow[j];
        const int t = q0 + 16 * w + 4 * qd + j;
        __hip_bfloat16* yr = y + (size_t)t * 2048 + h * 128 + lx;
#pragma unroll
        for (int nt = 0; nt < 8; ++nt) yr[nt * 16] = __float2bfloat16(O[nt][j] * inv);
    }
}

extern "C" void kernel_launch(void* const* d_in, const int* in_sizes, int n_in,
                              void* d_out, int out_size, void* d_ws, size_t ws_size,
                              hipStream_t stream) {
    const float* x         = (const float*)d_in[0];
    const float* freqs     = (const float*)d_in[1];
    const float* wq_a      = (const float*)d_in[2];
    const float* bq_a      = (const float*)d_in[3];
    const float* q_norm_w  = (const float*)d_in[4];
    const float* wq_b      = (const float*)d_in[5];
    const float* bq_b      = (const float*)d_in[6];
    const float* wkv_a     = (const float*)d_in[7];
    const float* bkv_a     = (const float*)d_in[8];
    const float* kv_norm_w = (const float*)d_in[9];
    const float* wkv_b     = (const float*)d_in[10];
    const float* bkv_b     = (const float*)d_in[11];
    const float* wo        = (const float*)d_in[12];
    const float* bo        = (const float*)d_in[13];
    float* out = (float*)d_out;

    // Workspace layout, ~76.3 MB total.
    char* p = (char*)d_ws;
    float* q_lat = (float*)p;                        p += (size_t)2048 * 1536 * 4;  // later hosts yb_bf
    float* kvpe  = (float*)p;                        p += (size_t)2048 * 640 * 4;
    __hip_bfloat16* x_bf      = (__hip_bfloat16*)p;  p += (size_t)2048 * 2048 * 2;  // later hosts vT
    __hip_bfloat16* q_lat_bf  = (__hip_bfloat16*)p;  p += (size_t)2048 * 1536 * 2;
    __hip_bfloat16* qb_bf     = (__hip_bfloat16*)p;  p += (size_t)2048 * 3072 * 2;
    __hip_bfloat16* kv_lat_bf = (__hip_bfloat16*)p;  p += (size_t)2048 * 512 * 2;
    __hip_bfloat16* kvb_bf    = (__hip_bfloat16*)p;  p += (size_t)2048 * 4096 * 2;
    __hip_bfloat16* kpe_bf    = (__hip_bfloat16*)p;  p += (size_t)2048 * 64 * 2;
    __hip_bfloat16* WA        = (__hip_bfloat16*)p;  p += (size_t)3072 * 1536 * 2;  // weight arena (max 9.44 MB)
    __hip_bfloat16* WB        = (__hip_bfloat16*)p;  p += (size_t)640 * 2048 * 2;   // padded wkv_a
    float* bkv_pad = (float*)p;                      p += (size_t)640 * 4;
    __hip_bfloat16* vT    = x_bf;                    // alias: x_bf dead after GEMM 2
    __hip_bfloat16* yb_bf = (__hip_bfloat16*)q_lat;  // alias: q_lat dead after rmsnorm

    // ---- casts & pads ----
    cast_bf16_kernel<<<4096, 256, 0, stream>>>(x, x_bf, 1048576, 1048576);
    cast_bf16_kernel<<<3072, 256, 0, stream>>>(wq_a, WA, 786432, 786432);
    // GEMM 1: q_lat = x @ wq_a^T + bq_a  (f32 out)
    gemm_mfma_kernel<float><<<dim3(12, 16), 256, 0, stream>>>(x_bf, 2048, WA, 2048, bq_a, q_lat, 1536, 2048);
    cast_bf16_kernel<<<1280, 256, 0, stream>>>(wkv_a, WB, 294912, 327680);
    pad_bias_kernel<<<3, 256, 0, stream>>>(bkv_a, bkv_pad, 576, 640);
    // GEMM 2: kvpe = x @ wkv_a^T + bkv_a  (f32 out, N padded to 640)
    gemm_mfma_kernel<float><<<dim3(5, 16), 256, 0, stream>>>(x_bf, 2048, WB, 2048, bkv_pad, kvpe, 640, 2048);
    // rmsnorm q -> bf16
    rmsnorm_kernel<<<2048, 256, 0, stream>>>(q_lat, q_lat_bf, q_norm_w, 1536, 1536, 1536);
    cast_bf16_kernel<<<4608, 256, 0, stream>>>(wq_b, WA, 1179648, 1179648);
    // GEMM 3: qb_bf = q_lat_bf @ wq_b^T + bq_b
    gemm_mfma_kernel<__hip_bfloat16><<<dim3(24, 16), 256, 0, stream>>>(q_lat_bf, 1536, WA, 1536, bq_b, qb_bf, 3072, 1536);
    rope_q_bf_kernel<<<4096, 256, 0, stream>>>(qb_bf, freqs);
    rope_k_bf_kernel<<<256, 256, 0, stream>>>(kvpe, freqs, kpe_bf);
    rmsnorm_kernel<<<2048, 256, 0, stream>>>(kvpe, kv_lat_bf, kv_norm_w, 512, 640, 512);
    cast_bf16_kernel<<<2048, 256, 0, stream>>>(wkv_b, WA, 524288, 524288);
    // GEMM 4: kvb_bf = kv_lat_bf @ wkv_b^T + bkv_b
    gemm_mfma_kernel<__hip_bfloat16><<<dim3(32, 16), 256, 0, stream>>>(kv_lat_bf, 512, WA, 512, bkv_b, kvb_bf, 4096, 512);
    pack_vT_kernel<<<dim3(32, 16), 256, 0, stream>>>(kvb_bf, vT);
    attn_mfma_kernel<<<dim3(32, 16), 256, 0, stream>>>(qb_bf, kvb_bf, kpe_bf, vT, yb_bf);
    cast_bf16_kernel<<<4096, 256, 0, stream>>>(wo, WA, 1048576, 1048576);
    // GEMM 5: out = yb_bf @ wo^T + bo  (f32 out)
    gemm_mfma_kernel<float><<<dim3(16, 16), 256, 0, stream>>>(yb_bf, 2048, WA, 2048, bo, out, 2048, 2048);
}